// Round 5
// baseline (143.852 us; speedup 1.0000x reference)
//
#include <hip/hip_runtime.h>
#include <hip/hip_bf16.h>

// B=8, S=4096, H=8, HKV=2, D=64, HID=512. M_TOT=32768, K=512.
// Pipeline:
//   K0 convert_x   : x f32 -> xb bf16                         (ws[0..32MB))
//   K1 transpose_w : [wq|wk|wv|wo] (KxN f32) -> wt bf16 NxK   (ws[80..81.3MB))
//   K2 gemm2<6>    : xb @ wt[0:768]  -> qkv bf16              (ws[32..80MB))
//   K3 attn_heads  : RoPE + analytic GQA 8x8 head-attn -> out2 (aliases xb)
//   K4 gemm2<4>    : out2 @ wt[768:1280] -> d_out f32
// GEMM: 256x128 tile, BK=32, 8 waves (4x2 of 64x64), dbuf LDS (48KB),
// global_load_lds width-16, bijective XCD swizzle, 2-deep counted-vmcnt
// pipeline (vmcnt(3) per step, never 0 in loop) + raw s_barrier + setprio.
// Scramble (ref transpose(0,2,1,3).reshape): attnout[b,t,h,d] ->
//   out2 row = h*512 + t/8, col = (t%8)*64 + d (per batch).

#define M_TOT 32768
#define K_DIM 512

typedef __bf16 bf16x8 __attribute__((ext_vector_type(8)));
typedef float f32x4 __attribute__((ext_vector_type(4)));
typedef unsigned short ushort8 __attribute__((ext_vector_type(8)));

__device__ __forceinline__ void gload_lds16(const __hip_bfloat16* g,
                                            __hip_bfloat16* l) {
  __builtin_amdgcn_global_load_lds(
      (const __attribute__((address_space(1))) unsigned int*)g,
      (__attribute__((address_space(3))) unsigned int*)l, 16, 0, 0);
}

__global__ __launch_bounds__(256) void convert_x(
    const float* __restrict__ x, __hip_bfloat16* __restrict__ xb) {
  size_t i = ((size_t)blockIdx.x * 256 + threadIdx.x) * 8;
  float4 a = *(const float4*)(x + i);
  float4 b = *(const float4*)(x + i + 4);
  ushort8 o;
  float va[8] = {a.x, a.y, a.z, a.w, b.x, b.y, b.z, b.w};
#pragma unroll
  for (int j = 0; j < 8; ++j) {
    __hip_bfloat16 t = __float2bfloat16(va[j]);
    o[j] = *(unsigned short*)&t;
  }
  *(ushort8*)(xb + i) = o;
}

// wt[n][k], n in [0,1280): n<512: wq col n; <640: wk col n-512; <768: wv col
// n-640; else wo col n-768.
__global__ __launch_bounds__(256) void transpose_w(
    const float* __restrict__ wq, const float* __restrict__ wk,
    const float* __restrict__ wv, const float* __restrict__ wo,
    __hip_bfloat16* __restrict__ wt) {
  __shared__ float tile[32][33];
  int n0 = blockIdx.x * 32, k0 = blockIdx.y * 32;
  const float* W;
  int ld, nc;
  if (n0 < 512)      { W = wq; ld = 512; nc = n0; }
  else if (n0 < 640) { W = wk; ld = 128; nc = n0 - 512; }
  else if (n0 < 768) { W = wv; ld = 128; nc = n0 - 640; }
  else               { W = wo; ld = 512; nc = n0 - 768; }
  int x = threadIdx.x & 31, y = threadIdx.x >> 5;
#pragma unroll
  for (int i = 0; i < 4; ++i)
    tile[y + 8 * i][x] = W[(size_t)(k0 + y + 8 * i) * ld + nc + x];
  __syncthreads();
#pragma unroll
  for (int i = 0; i < 4; ++i)
    wt[(size_t)(n0 + y + 8 * i) * 512 + k0 + x] =
        __float2bfloat16(tile[x][y + 8 * i]);
}

// MFMA GEMM: A (M_TOT x 512 bf16 row-major) @ Bt (N x 512 bf16, B^T) -> C.
// 256x128 tile, 8 waves as 4x2 of 64x64 sub-tiles. NT = N/128.
// LDS per buffer: A [kb 0..3][row 0..255][8bf16], B [kb 0..3][row 0..127][8bf16].
// Counted-vmcnt 2-deep pipeline: tile t computes while tile t+1's loads fly.
template <int NT, typename OutT>
__global__ __launch_bounds__(512) void gemm_mfma2(
    const __hip_bfloat16* __restrict__ A, const __hip_bfloat16* __restrict__ Bt,
    OutT* __restrict__ C) {
  constexpr int N = NT * 128;
  __shared__ __hip_bfloat16 Al[2][8192];
  __shared__ __hip_bfloat16 Bl[2][4096];
  const int tid = threadIdx.x;
  const int lane = tid & 63;
  const int w = tid >> 6;            // 0..7
  const int wr = w >> 1, wc = w & 1; // 4x2
  constexpr int NWG = 128 * NT;      // (M_TOT/256) * NT
  const int ng = (blockIdx.x & 7) * (NWG / 8) + (blockIdx.x >> 3);
  const int m0 = (ng / NT) * 256;
  const int n0 = (ng % NT) * 128;

  const __hip_bfloat16* gA0 =
      A + (size_t)(m0 + (tid & 255)) * 512 + (tid >> 8) * 8;
  const __hip_bfloat16* gA1 = gA0 + 16;  // kb+2
  const __hip_bfloat16* gB0 =
      Bt + (size_t)(n0 + (tid & 127)) * 512 + (tid >> 7) * 8;

  f32x4 acc[4][4] = {};
  const int kb = lane >> 4, fr = lane & 15;

  auto stage = [&](int buf, int kt) {
    int ko = kt * 32;
    gload_lds16(gA0 + ko, &Al[buf][(w * 64) * 8]);
    gload_lds16(gA1 + ko, &Al[buf][(512 + w * 64) * 8]);
    gload_lds16(gB0 + ko, &Bl[buf][(w * 64) * 8]);
  };

  // prologue: 2-deep prefetch (6 loads outstanding per thread)
  stage(0, 0);
  stage(1, 1);

  for (int ks = 0; ks < 16; ++ks) {
    // Wait for THIS tile's 3 loads (next tile's 3 stay in flight); each wave
    // waits its own, then barrier makes all waves' staging mutually visible.
    if (ks < 15)
      asm volatile("s_waitcnt vmcnt(3)" ::: "memory");
    else
      asm volatile("s_waitcnt vmcnt(0)" ::: "memory");
    __builtin_amdgcn_s_barrier();
    __builtin_amdgcn_sched_barrier(0);

    bf16x8 af[4], bfr[4];
    const int cur = ks & 1;
#pragma unroll
    for (int mi = 0; mi < 4; ++mi)
      af[mi] =
          *(const bf16x8*)&Al[cur][(kb * 256 + wr * 64 + mi * 16 + fr) * 8];
#pragma unroll
    for (int ni = 0; ni < 4; ++ni)
      bfr[ni] =
          *(const bf16x8*)&Bl[cur][(kb * 128 + wc * 64 + ni * 16 + fr) * 8];
    __builtin_amdgcn_s_setprio(1);
#pragma unroll
    for (int mi = 0; mi < 4; ++mi)
#pragma unroll
      for (int ni = 0; ni < 4; ++ni)
        acc[mi][ni] = __builtin_amdgcn_mfma_f32_16x16x32_bf16(
            af[mi], bfr[ni], acc[mi][ni], 0, 0, 0);
    __builtin_amdgcn_s_setprio(0);

    __builtin_amdgcn_s_barrier();  // all waves done reading buf[cur]
    if (ks + 2 < 16) stage(cur, ks + 2);
  }

  // C/D layout: col=lane&15, row=(lane>>4)*4+reg  [m89]
#pragma unroll
  for (int mi = 0; mi < 4; ++mi) {
#pragma unroll
    for (int ni = 0; ni < 4; ++ni) {
      int col = n0 + wc * 64 + ni * 16 + (lane & 15);
#pragma unroll
      for (int r = 0; r < 4; ++r) {
        int row = m0 + wr * 64 + mi * 16 + (lane >> 4) * 4 + r;
        if constexpr (sizeof(OutT) == 2)
          C[(size_t)row * N + col] = __float2bfloat16(acc[mi][ni][r]);
        else
          C[(size_t)row * N + col] = acc[mi][ni][r];
      }
    }
  }
}

// One wave per (b,t) position: RoPE + analytic GQA softmax over 8 heads.
__global__ __launch_bounds__(256) void attn_heads(
    const __hip_bfloat16* __restrict__ qkv, const float* __restrict__ fcos,
    const float* __restrict__ fsin, __hip_bfloat16* __restrict__ out2) {
  const int lane = threadIdx.x & 63;
  const int wid = blockIdx.x * (blockDim.x >> 6) + (threadIdx.x >> 6);
  const int b = wid >> 12;
  const int t = wid & 4095;
  const size_t row = (size_t)wid * 768;

  float q[8], k[2], v[2];
#pragma unroll
  for (int h = 0; h < 8; ++h) q[h] = __bfloat162float(qkv[row + h * 64 + lane]);
#pragma unroll
  for (int c = 0; c < 2; ++c) {
    k[c] = __bfloat162float(qkv[row + 512 + c * 64 + lane]);
    v[c] = __bfloat162float(qkv[row + 640 + c * 64 + lane]);
  }
  const float cc = fcos[t * 32 + (lane >> 1)];
  const float ss = fsin[t * 32 + (lane >> 1)];
  const bool odd = lane & 1;
#pragma unroll
  for (int h = 0; h < 8; ++h) {
    float other = __shfl_xor(q[h], 1);
    q[h] = odd ? (other * ss + q[h] * cc) : (q[h] * cc - other * ss);
  }
#pragma unroll
  for (int c = 0; c < 2; ++c) {
    float other = __shfl_xor(k[c], 1);
    k[c] = odd ? (other * ss + k[c] * cc) : (k[c] * cc - other * ss);
  }
  float dot[8][2];
#pragma unroll
  for (int h = 0; h < 8; ++h)
#pragma unroll
    for (int c = 0; c < 2; ++c) {
      float p = q[h] * k[c];
#pragma unroll
      for (int off = 32; off >= 1; off >>= 1) p += __shfl_xor(p, off);
      dot[h][c] = p * 0.125f;
    }
#pragma unroll
  for (int h = 0; h < 8; ++h) {
    int c0 = (h + 1 < 4) ? (h + 1) : 4;
    int c1 = (h + 1) - c0;
    float out;
    if (c1 > 0) {
      float s0 = dot[h][0], s1 = dot[h][1];
      float m = fmaxf(s0, s1);
      float e0 = expf(s0 - m), e1 = expf(s1 - m);
      float denom = (float)c0 * e0 + (float)c1 * e1;
      out = ((float)c0 * e0 * v[0] + (float)c1 * e1 * v[1]) / denom;
    } else {
      out = v[0];
    }
    int tp = h * 512 + (t >> 3);
    int cp = (t & 7) * 64 + lane;
    out2[((size_t)(b * 4096 + tp)) * 512 + cp] = __float2bfloat16(out);
  }
}

extern "C" void kernel_launch(void* const* d_in, const int* in_sizes, int n_in,
                              void* d_out, int out_size, void* d_ws,
                              size_t ws_size, hipStream_t stream) {
  const float* x    = (const float*)d_in[0];
  const float* fcos = (const float*)d_in[1];
  const float* fsin = (const float*)d_in[2];
  const float* wq   = (const float*)d_in[3];
  const float* wk   = (const float*)d_in[4];
  const float* wv   = (const float*)d_in[5];
  const float* wo   = (const float*)d_in[6];
  float* out = (float*)d_out;

  __hip_bfloat16* xb   = (__hip_bfloat16*)d_ws;  // 32MB
  __hip_bfloat16* out2 = xb;                      // alias (xb dead after gemm qkv)
  __hip_bfloat16* qkv  = (__hip_bfloat16*)((char*)d_ws + (size_t)M_TOT * 512 * 2);  // 48MB
  __hip_bfloat16* wt   = (__hip_bfloat16*)((char*)d_ws + (size_t)M_TOT * 512 * 2 +
                                           (size_t)M_TOT * 768 * 2);  // 1.25MB

  convert_x<<<dim3(M_TOT * 512 / 8 / 256), 256, 0, stream>>>(x, xb);
  transpose_w<<<dim3(1280 / 32, 512 / 32), 256, 0, stream>>>(wq, wk, wv, wo, wt);
  gemm_mfma2<6, __hip_bfloat16><<<dim3(768), 512, 0, stream>>>(xb, wt, qkv);
  attn_heads<<<dim3(M_TOT / 4), 256, 0, stream>>>(qkv, fcos, fsin, out2);
  gemm_mfma2<4, float><<<dim3(512), 512, 0, stream>>>(out2, wt + 768 * 512, out);
}

// Round 6
// 111.826 us; speedup vs baseline: 1.2864x; 1.2864x over previous
//
#include <hip/hip_runtime.h>
#include <hip/hip_bf16.h>

// B=8, S=4096, H=8, HKV=2, D=64, HID=512. M_TOT=32768, K=512.
// Pipeline:
//   K0 convert_x   : x f32 -> xb bf16                          (ws[0..32MB))
//   K1 transpose_w : weights -> wt bf16, pre-tiled in LDS-slot order
//                    (10 col-blocks of 128; block nb, slot (kg,col) 16B)
//   K2 gemm_persist<6,0> : xb @ wt[blk 0..5]  -> qkv bf16      (ws[32..80MB))
//   K3 attn_heads  : RoPE + analytic GQA 8x8 head-attn -> out2 (aliases xb)
//   K4 gemm_persist<4,6> : out2 @ wt[blk 6..9] -> d_out f32
// GEMM structure: block = 512 thr (8 waves), owns 512 rows x 128 cols.
// Whole B-panel (128 cols x 512 K = 128KB) persistent in LDS, staged once
// (16 linear global_load_lds per thread, ONE barrier). K-loop has NO
// barriers: each wave independently streams its own 64 A-rows from global
// (registers) against LDS B. acc[4][8] f32x4. Bijective XCD swizzle.
// Scramble (ref transpose(0,2,1,3).reshape): attnout[b,t,h,d] ->
//   out2 row = h*512 + t/8, col = (t%8)*64 + d (per batch).

#define M_TOT 32768
#define K_DIM 512

typedef __bf16 bf16x8 __attribute__((ext_vector_type(8)));
typedef float f32x4 __attribute__((ext_vector_type(4)));
typedef unsigned short ushort8 __attribute__((ext_vector_type(8)));

__device__ __forceinline__ void gload_lds16(const __hip_bfloat16* g,
                                            __hip_bfloat16* l) {
  __builtin_amdgcn_global_load_lds(
      (const __attribute__((address_space(1))) unsigned int*)g,
      (__attribute__((address_space(3))) unsigned int*)l, 16, 0, 0);
}

__global__ __launch_bounds__(256) void convert_x(
    const float* __restrict__ x, __hip_bfloat16* __restrict__ xb) {
  size_t i = ((size_t)blockIdx.x * 256 + threadIdx.x) * 8;
  float4 a = *(const float4*)(x + i);
  float4 b = *(const float4*)(x + i + 4);
  ushort8 o;
  float va[8] = {a.x, a.y, a.z, a.w, b.x, b.y, b.z, b.w};
#pragma unroll
  for (int j = 0; j < 8; ++j) {
    __hip_bfloat16 t = __float2bfloat16(va[j]);
    o[j] = *(unsigned short*)&t;
  }
  *(ushort8*)(xb + i) = o;
}

// wt pre-tiled: col n (global 0..1279), k: nb=n>>7, col=n&127, kg=k>>3,
// element idx = nb*65536 + (kg*128 + col)*8 + (k&7).
__global__ __launch_bounds__(256) void transpose_w(
    const float* __restrict__ wq, const float* __restrict__ wk,
    const float* __restrict__ wv, const float* __restrict__ wo,
    __hip_bfloat16* __restrict__ wt) {
  __shared__ float tile[32][33];
  int n0 = blockIdx.x * 32, k0 = blockIdx.y * 32;
  const float* W;
  int ld, nc;
  if (n0 < 512)      { W = wq; ld = 512; nc = n0; }
  else if (n0 < 640) { W = wk; ld = 128; nc = n0 - 512; }
  else if (n0 < 768) { W = wv; ld = 128; nc = n0 - 640; }
  else               { W = wo; ld = 512; nc = n0 - 768; }
  int x = threadIdx.x & 31, y = threadIdx.x >> 5;
#pragma unroll
  for (int i = 0; i < 4; ++i)
    tile[y + 8 * i][x] = W[(size_t)(k0 + y + 8 * i) * ld + nc + x];
  __syncthreads();
#pragma unroll
  for (int i = 0; i < 4; ++i) {
    int n = n0 + y + 8 * i, k = k0 + x;
    wt[((size_t)(n >> 7) << 16) + ((size_t)((k >> 3) * 128 + (n & 127))) * 8 +
       (k & 7)] = __float2bfloat16(tile[x][y + 8 * i]);
  }
}

// Persistent-B register-streaming GEMM.
// A (M_TOT x 512 bf16 row-major), wt slot-tiled, C (M_TOT x NT*128).
// Block: 512 rows x 128 cols; wave w owns rows [w*64, w*64+64).
template <int NT, int NB0, typename OutT>
__global__ __launch_bounds__(512, 2) void gemm_persist(
    const __hip_bfloat16* __restrict__ A, const __hip_bfloat16* __restrict__ wt,
    OutT* __restrict__ C) {
  constexpr int N = NT * 128;
  __shared__ __hip_bfloat16 Bl[65536];  // 128KB: slot(kg 0..63, col 0..127) 16B
  const int tid = threadIdx.x;
  const int lane = tid & 63;
  const int w = tid >> 6;  // 0..7
  constexpr int NWG = (M_TOT / 512) * NT;
  const int ng = (blockIdx.x & 7) * (NWG / 8) + (blockIdx.x >> 3);
  const int m0 = (ng / NT) * 512;
  const int n0 = (ng % NT) * 128;

  // Stage whole B panel: 8192 slots, 16 linear wave-loads per thread.
  {
    const __hip_bfloat16* Bblk = wt + ((size_t)(NB0 + ng % NT) << 16);
#pragma unroll
    for (int j = 0; j < 16; ++j)
      gload_lds16(Bblk + (size_t)(j * 512 + w * 64 + lane) * 8,
                  &Bl[(j * 512 + w * 64) * 8]);
  }
  asm volatile("s_waitcnt vmcnt(0)" ::: "memory");
  __syncthreads();  // ONLY barrier; Bl read-only hereafter.

  const int kbq = lane >> 4, fr = lane & 15;
  // A frag mi at step ks: row m0 + w*64 + mi*16 + fr, k = ks*32 + kbq*8.
  const __hip_bfloat16* pA =
      A + (size_t)(m0 + w * 64 + fr) * 512 + kbq * 8;

  f32x4 acc[4][8] = {};
  bf16x8 a[2][4];
#pragma unroll
  for (int mi = 0; mi < 4; ++mi)
    a[0][mi] = *(const bf16x8*)(pA + mi * 16 * 512);

#pragma unroll
  for (int ks = 0; ks < 16; ++ks) {
    bf16x8 b[8];
#pragma unroll
    for (int ni = 0; ni < 8; ++ni)
      b[ni] = *(const bf16x8*)&Bl[((ks * 4 + kbq) * 128 + ni * 16 + fr) * 8];
    if (ks < 15) {
#pragma unroll
      for (int mi = 0; mi < 4; ++mi)
        a[(ks + 1) & 1][mi] =
            *(const bf16x8*)(pA + mi * 16 * 512 + (ks + 1) * 32);
    }
#pragma unroll
    for (int mi = 0; mi < 4; ++mi)
#pragma unroll
      for (int ni = 0; ni < 8; ++ni)
        acc[mi][ni] = __builtin_amdgcn_mfma_f32_16x16x32_bf16(
            a[ks & 1][mi], b[ni], acc[mi][ni], 0, 0, 0);
  }

  // C/D layout: col=lane&15, row=(lane>>4)*4+reg  [m89]
#pragma unroll
  for (int mi = 0; mi < 4; ++mi) {
#pragma unroll
    for (int ni = 0; ni < 8; ++ni) {
      int col = n0 + ni * 16 + (lane & 15);
#pragma unroll
      for (int r = 0; r < 4; ++r) {
        int row = m0 + w * 64 + mi * 16 + (lane >> 4) * 4 + r;
        if constexpr (sizeof(OutT) == 2)
          C[(size_t)row * N + col] = __float2bfloat16(acc[mi][ni][r]);
        else
          C[(size_t)row * N + col] = acc[mi][ni][r];
      }
    }
  }
}

// One wave per (b,t) position: RoPE + analytic GQA softmax over 8 heads.
__global__ __launch_bounds__(256) void attn_heads(
    const __hip_bfloat16* __restrict__ qkv, const float* __restrict__ fcos,
    const float* __restrict__ fsin, __hip_bfloat16* __restrict__ out2) {
  const int lane = threadIdx.x & 63;
  const int wid = blockIdx.x * (blockDim.x >> 6) + (threadIdx.x >> 6);
  const int b = wid >> 12;
  const int t = wid & 4095;
  const size_t row = (size_t)wid * 768;

  float q[8], k[2], v[2];
#pragma unroll
  for (int h = 0; h < 8; ++h) q[h] = __bfloat162float(qkv[row + h * 64 + lane]);
#pragma unroll
  for (int c = 0; c < 2; ++c) {
    k[c] = __bfloat162float(qkv[row + 512 + c * 64 + lane]);
    v[c] = __bfloat162float(qkv[row + 640 + c * 64 + lane]);
  }
  const float cc = fcos[t * 32 + (lane >> 1)];
  const float ss = fsin[t * 32 + (lane >> 1)];
  const bool odd = lane & 1;
#pragma unroll
  for (int h = 0; h < 8; ++h) {
    float other = __shfl_xor(q[h], 1);
    q[h] = odd ? (other * ss + q[h] * cc) : (q[h] * cc - other * ss);
  }
#pragma unroll
  for (int c = 0; c < 2; ++c) {
    float other = __shfl_xor(k[c], 1);
    k[c] = odd ? (other * ss + k[c] * cc) : (k[c] * cc - other * ss);
  }
  float dot[8][2];
#pragma unroll
  for (int h = 0; h < 8; ++h)
#pragma unroll
    for (int c = 0; c < 2; ++c) {
      float p = q[h] * k[c];
#pragma unroll
      for (int off = 32; off >= 1; off >>= 1) p += __shfl_xor(p, off);
      dot[h][c] = p * 0.125f;
    }
#pragma unroll
  for (int h = 0; h < 8; ++h) {
    int c0 = (h + 1 < 4) ? (h + 1) : 4;
    int c1 = (h + 1) - c0;
    float out;
    if (c1 > 0) {
      float s0 = dot[h][0], s1 = dot[h][1];
      float m = fmaxf(s0, s1);
      float e0 = expf(s0 - m), e1 = expf(s1 - m);
      float denom = (float)c0 * e0 + (float)c1 * e1;
      out = ((float)c0 * e0 * v[0] + (float)c1 * e1 * v[1]) / denom;
    } else {
      out = v[0];
    }
    int tp = h * 512 + (t >> 3);
    int cp = (t & 7) * 64 + lane;
    out2[((size_t)(b * 4096 + tp)) * 512 + cp] = __float2bfloat16(out);
  }
}

extern "C" void kernel_launch(void* const* d_in, const int* in_sizes, int n_in,
                              void* d_out, int out_size, void* d_ws,
                              size_t ws_size, hipStream_t stream) {
  const float* x    = (const float*)d_in[0];
  const float* fcos = (const float*)d_in[1];
  const float* fsin = (const float*)d_in[2];
  const float* wq   = (const float*)d_in[3];
  const float* wk   = (const float*)d_in[4];
  const float* wv   = (const float*)d_in[5];
  const float* wo   = (const float*)d_in[6];
  float* out = (float*)d_out;

  __hip_bfloat16* xb   = (__hip_bfloat16*)d_ws;  // 32MB
  __hip_bfloat16* out2 = xb;                      // alias (xb dead after qkv gemm)
  __hip_bfloat16* qkv  = (__hip_bfloat16*)((char*)d_ws + (size_t)M_TOT * 512 * 2);  // 48MB
  __hip_bfloat16* wt   = (__hip_bfloat16*)((char*)d_ws + (size_t)M_TOT * 512 * 2 +
                                           (size_t)M_TOT * 768 * 2);  // 1.25MB

  convert_x<<<dim3(M_TOT * 512 / 8 / 256), 256, 0, stream>>>(x, xb);
  transpose_w<<<dim3(1280 / 32, 512 / 32), 256, 0, stream>>>(wq, wk, wv, wo, wt);
  gemm_persist<6, 0, __hip_bfloat16><<<dim3(384), 512, 0, stream>>>(xb, wt, qkv);
  attn_heads<<<dim3(M_TOT / 4), 256, 0, stream>>>(qkv, fcos, fsin, out2);
  gemm_persist<4, 6, float><<<dim3(256), 512, 0, stream>>>(out2, wt, out);
}